// Round 3
// baseline (259.050 us; speedup 1.0000x reference)
//
#include <hip/hip_runtime.h>
#include <math.h>

#define NH    8
#define DIM   256
#define NQ    8400
#define BATCH 4
#define STOT  8400
#define MQ    (BATCH * NQ)   // 33600

typedef _Float16 f16;
typedef __attribute__((ext_vector_type(2))) _Float16 f16x2;
typedef __attribute__((ext_vector_type(8))) _Float16 f16x8;
typedef __attribute__((ext_vector_type(4))) float  f32x4;

// Async global->LDS, 16B per lane. LDS dest is wave-uniform base + lane*16.
static __device__ __forceinline__ void gl_lds16(const void* g, void* l) {
    __builtin_amdgcn_global_load_lds(
        (const __attribute__((address_space(1))) unsigned int*)g,
        (__attribute__((address_space(3))) unsigned int*)(unsigned int)(unsigned long long)l,
        16, 0, 0);
}

// ---------------------------------------------------------------------------
// prep_feat: z=0..3 feat transpose+cvt (3 levels concat) for batch z into
// Af[MQ][256] fp16; z=4: weight transposes + bias concat. (No query prep:
// the GEMM converts query fp32 in-register.)
__global__ __launch_bounds__(256) void prep_feat(
    const float* __restrict__ feat0, const float* __restrict__ feat1,
    const float* __restrict__ feat2,
    const float* __restrict__ W_val, const float* __restrict__ W_out,
    const float* __restrict__ W_off, const float* __restrict__ W_attn,
    const float* __restrict__ b_off, const float* __restrict__ b_attn,
    f16* __restrict__ Af, f16* __restrict__ Wvt, f16* __restrict__ Wot,
    f16* __restrict__ Wch, float* __restrict__ bcat)
{
    const int z = blockIdx.z;
    const int t = threadIdx.x;
    __shared__ float tile[32][33];
    const int c = t & 31, r = t >> 5;

    if (z == 4) {
        const int xb = blockIdx.x;
        if (xb > 25) return;
        if (xb == 25) {
            if (blockIdx.y == 0)
                for (int i = t; i < 288; i += 256)
                    bcat[i] = (i < 192) ? b_off[i] : b_attn[i - 192];
            return;
        }
        const float* W; f16* oH; int Nw, n0, nb;
        if (xb < 8)       { W = W_val;  oH = Wvt; Nw = 256; n0 = 0;   nb = xb * 32; }
        else if (xb < 16) { W = W_out;  oH = Wot; Nw = 256; n0 = 0;   nb = (xb - 8) * 32; }
        else if (xb < 22) { W = W_off;  oH = Wch; Nw = 192; n0 = 0;   nb = (xb - 16) * 32; }
        else              { W = W_attn; oH = Wch; Nw = 96;  n0 = 192; nb = (xb - 22) * 32; }
        const int k0 = blockIdx.y * 32;
        #pragma unroll
        for (int i = 0; i < 4; ++i) {
            int k = k0 + r + i * 8, n = nb + c;
            tile[r + i * 8][c] = (n < Nw) ? W[(size_t)k * Nw + n] : 0.f;
        }
        __syncthreads();
        #pragma unroll
        for (int i = 0; i < 4; ++i) {
            int n = nb + r + i * 8, k = k0 + c;
            if (n < Nw)
                oH[(size_t)(n0 + n) * 256 + k] = (f16)tile[c][r + i * 8];
        }
        return;
    }

    const int b = z;
    const int s0 = blockIdx.x * 32, k0 = blockIdx.y * 32;
    if (s0 >= 8400) return;
    const float* f0b = feat0 + (size_t)b * 256 * 6400;
    const float* f1b = feat1 + (size_t)b * 256 * 1600;
    const float* f2b = feat2 + (size_t)b * 256 * 400;
    #pragma unroll
    for (int i = 0; i < 4; ++i) {
        int rr = r + i * 8;
        int s = s0 + c;
        float v = 0.f;
        if (s < 8400) {
            const float* fp; int S, sl;
            if (s < 6400)      { fp = f0b; S = 6400; sl = s; }
            else if (s < 8000) { fp = f1b; S = 1600; sl = s - 6400; }
            else               { fp = f2b; S = 400;  sl = s - 8000; }
            v = fp[(size_t)(k0 + rr) * S + sl];
        }
        tile[rr][c] = v;
    }
    __syncthreads();
    #pragma unroll
    for (int i = 0; i < 4; ++i) {
        int s = s0 + r + i * 8, k = k0 + c;
        if (s < 8400)
            Af[((size_t)b * 8400 + s) * 256 + k] = (f16)tile[c][r + i * 8];
    }
}

// ---------------------------------------------------------------------------
// B-stationary GEMM, barrier-free K-loop.
// Tile M=128 (4 waves x 32 rows), N=64, K=256 fully unrolled.
// B-slice [64][256] fp16 staged ONCE into 32KB LDS (gl_lds16, XOR chunk
// swizzle: chunk c of row n stored at position c^(n&7)).
// A held entirely in registers as MFMA fragments (64 VGPR/wave): per-lane 16B
// loads at row-stride 512B -> each 64B line fully consumed by 4 quad-lanes.
// One __syncthreads total; K-loop is pure ds_read_b128 + MFMA.
// KIND 0: x<4 val (A=Af fp16), x>=4 query (A=query fp32, cvt in-reg, N=288).
// KIND 1: out projection (A=outh fp16).
template<int KIND>
__global__ __launch_bounds__(256) void gemm_bs(
    const float* __restrict__ query,
    const f16* __restrict__ Af,
    const f16* __restrict__ outh_in,
    const f16* __restrict__ Wvt, const f16* __restrict__ Wch,
    const f16* __restrict__ Wot,
    const float* __restrict__ b_val, const float* __restrict__ bcat,
    const float* __restrict__ b_out,
    f16* __restrict__ valh, float* __restrict__ rawo, f16* __restrict__ attnh,
    float* __restrict__ Cf)
{
    __shared__ __align__(16) f16 Bsl[2048 * 8];   // 32 KB: 64 rows x 32 chunks x 16B

    const int t = threadIdx.x;
    const int lane = t & 63, w = t >> 6;
    const int l15 = lane & 15, quad = lane >> 4;

    const bool qpath = (KIND == 0) && (blockIdx.x >= 4);
    const int bn = qpath ? (blockIdx.x - 4) * 64 : blockIdx.x * 64;
    const int bm = blockIdx.y * 128;
    const int N  = qpath ? 288 : 256;
    const f16* Bg = (KIND == 0) ? (qpath ? Wch : Wvt) : Wot;
    const float* bias = (KIND == 0) ? (qpath ? bcat : b_val) : b_out;

    // ---- stage B slice (once): slot = n*32 + c', holds chunk c = c'^(n&7)
    #pragma unroll
    for (int i = 0; i < 8; ++i) {
        int slot = i * 256 + t;
        int n = slot >> 5, cp = slot & 31;
        int cc = cp ^ (n & 7);
        int gn = bn + n; if (gn > N - 1) gn = N - 1;
        gl_lds16(Bg + (size_t)gn * 256 + cc * 8, &Bsl[slot * 8]);
    }

    // ---- A fragments into registers: wave's 32 rows x full K
    const int r0 = bm + w * 32 + l15;
    f16x8 areg[2][8];
    if (KIND == 0 && qpath) {
        #pragma unroll
        for (int mt = 0; mt < 2; ++mt) {
            int row = r0 + mt * 16; if (row > MQ - 1) row = MQ - 1;
            const float* ap = query + (size_t)row * 256 + quad * 8;
            #pragma unroll
            for (int kt = 0; kt < 8; ++kt) {
                float4 a = *(const float4*)(ap + kt * 32);
                float4 b = *(const float4*)(ap + kt * 32 + 4);
                f16x8 h;
                h[0] = (f16)a.x; h[1] = (f16)a.y; h[2] = (f16)a.z; h[3] = (f16)a.w;
                h[4] = (f16)b.x; h[5] = (f16)b.y; h[6] = (f16)b.z; h[7] = (f16)b.w;
                areg[mt][kt] = h;
            }
        }
    } else {
        const f16* Ag = (KIND == 0) ? Af : outh_in;
        #pragma unroll
        for (int mt = 0; mt < 2; ++mt) {
            int row = r0 + mt * 16; if (row > MQ - 1) row = MQ - 1;
            const f16* ap = Ag + (size_t)row * 256 + quad * 8;
            #pragma unroll
            for (int kt = 0; kt < 8; ++kt)
                areg[mt][kt] = *(const f16x8*)(ap + kt * 32);
        }
    }

    f32x4 acc[2][4];
    #pragma unroll
    for (int i = 0; i < 2; ++i)
        #pragma unroll
        for (int j = 0; j < 4; ++j)
            acc[i][j] = (f32x4){0.f, 0.f, 0.f, 0.f};

    __syncthreads();   // the only barrier: drains B staging (and A loads)

    #pragma unroll
    for (int kt = 0; kt < 8; ++kt) {
        f16x8 bfv[4];
        #pragma unroll
        for (int nt = 0; nt < 4; ++nt) {
            int n = nt * 16 + l15;
            int cp = (kt * 4 + quad) ^ (n & 7);
            bfv[nt] = *(const f16x8*)&Bsl[((size_t)n * 32 + cp) * 8];
        }
        #pragma unroll
        for (int mt = 0; mt < 2; ++mt)
            #pragma unroll
            for (int nt = 0; nt < 4; ++nt)
                acc[mt][nt] = __builtin_amdgcn_mfma_f32_16x16x32_f16(
                                  areg[mt][kt], bfv[nt], acc[mt][nt], 0, 0, 0);
    }

    #pragma unroll
    for (int nt = 0; nt < 4; ++nt) {
        int col = bn + nt * 16 + l15;
        float bv = (col < N) ? bias[col] : 0.f;
        #pragma unroll
        for (int mt = 0; mt < 2; ++mt) {
            int row0 = bm + w * 32 + mt * 16 + quad * 4;
            #pragma unroll
            for (int r = 0; r < 4; ++r) {
                int row = row0 + r;
                if (row >= MQ || col >= N) continue;
                float v = acc[mt][nt][r] + bv;
                if (KIND == 1) {
                    Cf[(size_t)row * 256 + col] = v;
                } else if (!qpath) {
                    int bb = row / STOT, s = row - bb * STOT;
                    int h = col >> 5, c = col & 31;
                    valh[(((size_t)(bb * 8 + h)) * STOT + s) * 32 + c] = (f16)v;
                } else if (col < 192) {
                    rawo[(size_t)row * 192 + col] = 0.5f * tanhf(v);  // tanh hoisted
                } else {
                    attnh[(size_t)row * 96 + (col - 192)] = (f16)v;
                }
            }
        }
    }
}

// ---------------------------------------------------------------------------
// Sampler v7: packed (w16|idx16) LDS, tanh pre-applied upstream, packed-fp16
// inner loop, fp32 flush per 12 corners. XCD-swizzled.
__global__ __launch_bounds__(256) void sample_v7(
    const f16* __restrict__ valh,        // [B*8][STOT][32] fp16
    const float* __restrict__ off05,     // [MQ][192] = 0.5*tanh(raw) (fp32)
    const f16* __restrict__ attnh,       // [MQ][96] fp16
    const float* __restrict__ refp,      // [MQ][2]
    f16* __restrict__ out_h)             // [MQ][256] fp16
{
    const int bx = blockIdx.x;
    const int xcd = bx & 7;
    const int b = xcd >> 1;
    const int qi = (bx >> 3) * 2 + (xcd & 1);
    const int bq0 = b * NQ + qi * 8;
    const int t = threadIdx.x;

    __shared__ unsigned s_pk[8][96][4];   // (w16<<16)|idx16 per corner
    __shared__ float    s_m[8][8];
    __shared__ float    s_inv[8][8];

    if (t < 64) {
        int q = t >> 3, h = t & 7;
        const f16* a = attnh + (size_t)(bq0 + q) * 96 + h * 12;
        float m = (float)a[0];
        #pragma unroll
        for (int j = 1; j < 12; ++j) m = fmaxf(m, (float)a[j]);
        float s = 0.f;
        #pragma unroll
        for (int j = 0; j < 12; ++j) s += expf((float)a[j] - m);
        s_m[q][h] = m;
        s_inv[q][h] = 1.f / s;
    }
    __syncthreads();

    for (int i = t; i < 768; i += 256) {
        int q = i / 96, p = i - q * 96;
        int h = p / 12, lp = p - h * 12, l = lp >> 2;
        const int dims[3]   = {80, 40, 20};
        const int bases_[3] = {0, 6400, 8000};
        int Wl = dims[l], base = bases_[l];
        float logit = (float)attnh[(size_t)(bq0 + q) * 96 + p];
        float aw = expf(logit - s_m[q][h]) * s_inv[q][h];
        size_t ro = (size_t)(bq0 + q) * 192 + h * 24 + lp * 2;
        float ox = off05[ro], oy = off05[ro + 1];
        float rx = refp[(size_t)(bq0 + q) * 2];
        float ry = refp[(size_t)(bq0 + q) * 2 + 1];
        float ix = (rx + ox) * Wl - 0.5f;
        float iy = (ry + oy) * Wl - 0.5f;
        float x0f = floorf(ix), y0f = floorf(iy);
        float fx = ix - x0f, fy = iy - y0f;
        int x0 = (int)x0f, y0 = (int)y0f;
        float w00 = (1.f - fx) * (1.f - fy) * aw;
        float w01 = fx * (1.f - fy) * aw;
        float w10 = (1.f - fx) * fy * aw;
        float w11 = fx * fy * aw;
        bool vx0 = (unsigned)x0 < (unsigned)Wl;
        bool vx1 = (unsigned)(x0 + 1) < (unsigned)Wl;
        bool vy0 = (unsigned)y0 < (unsigned)Wl;
        bool vy1 = (unsigned)(y0 + 1) < (unsigned)Wl;
        int row0 = base + y0 * Wl, row1 = row0 + Wl;
        float ws[4] = { vx0 && vy0 ? w00 : 0.f, vx1 && vy0 ? w01 : 0.f,
                        vx0 && vy1 ? w10 : 0.f, vx1 && vy1 ? w11 : 0.f };
        int   is[4] = { vx0 && vy0 ? row0 + x0 : 0, vx1 && vy0 ? row0 + x0 + 1 : 0,
                        vx0 && vy1 ? row1 + x0 : 0, vx1 && vy1 ? row1 + x0 + 1 : 0 };
        #pragma unroll
        for (int k = 0; k < 4; ++k) {
            unsigned short us = __builtin_bit_cast(unsigned short, (f16)ws[k]);
            s_pk[q][p][k] = ((unsigned)us << 16) | (unsigned)is[k];
        }
    }
    __syncthreads();

    const int q = t >> 5;
    const int h = (t >> 2) & 7;
    const int l4 = t & 3;
    const uint4* vb4 = (const uint4*)(valh + (size_t)(b * 8 + h) * STOT * 32);
    const unsigned* pkp = &s_pk[q][h * 12][0];
    float accf[8] = {};
    #pragma unroll
    for (int pp = 0; pp < 4; ++pp) {
        unsigned pk[12]; uint4 v[12];
        #pragma unroll
        for (int k = 0; k < 12; ++k) pk[k] = pkp[pp * 12 + k];
        #pragma unroll
        for (int k = 0; k < 12; ++k) v[k] = vb4[(size_t)(pk[k] & 0xffffu) * 4 + l4];
        f16x2 a0 = (f16x2)(f16)0, a1 = a0, a2 = a0, a3 = a0;
        #pragma unroll
        for (int k = 0; k < 12; ++k) {
            // (w,w) from packed word via v_perm_b32 (bytes 2,3,2,3)
            f16x2 wv = __builtin_bit_cast(f16x2,
                        __builtin_amdgcn_perm(pk[k], pk[k], 0x03020302u));
            a0 += wv * __builtin_bit_cast(f16x2, v[k].x);
            a1 += wv * __builtin_bit_cast(f16x2, v[k].y);
            a2 += wv * __builtin_bit_cast(f16x2, v[k].z);
            a3 += wv * __builtin_bit_cast(f16x2, v[k].w);
        }
        accf[0] += (float)a0[0]; accf[1] += (float)a0[1];
        accf[2] += (float)a1[0]; accf[3] += (float)a1[1];
        accf[4] += (float)a2[0]; accf[5] += (float)a2[1];
        accf[6] += (float)a3[0]; accf[7] += (float)a3[1];
    }
    f16x8 ob;
    #pragma unroll
    for (int c = 0; c < 8; ++c) ob[c] = (f16)accf[c];
    *(f16x8*)(out_h + (size_t)(bq0 + q) * 256 + h * 32 + l4 * 8) = ob;
}

// ---------------------------------------------------------------------------
extern "C" void kernel_launch(void* const* d_in, const int* in_sizes, int n_in,
                              void* d_out, int out_size, void* d_ws, size_t ws_size,
                              hipStream_t stream)
{
    const float* query  = (const float*)d_in[0];
    const float* feat0  = (const float*)d_in[1];
    const float* feat1  = (const float*)d_in[2];
    const float* feat2  = (const float*)d_in[3];
    const float* refp   = (const float*)d_in[4];
    const float* W_off  = (const float*)d_in[5];
    const float* b_off  = (const float*)d_in[6];
    const float* W_attn = (const float*)d_in[7];
    const float* b_attn = (const float*)d_in[8];
    const float* W_val  = (const float*)d_in[9];
    const float* b_val  = (const float*)d_in[10];
    const float* W_out  = (const float*)d_in[11];
    const float* b_out  = (const float*)d_in[12];
    float* out = (float*)d_out;

    // workspace (~67 MB)
    f16*   valh  = (f16*)d_ws;                               // MQ*256 fp16
    float* rawo  = (float*)(valh + (size_t)MQ * 256);        // MQ*192 f32 (0.5*tanh)
    f16*   attnh = (f16*)(rawo + (size_t)MQ * 192);          // MQ*96 fp16
    f16*   Af    = attnh + (size_t)MQ * 96;                  // MQ*256 fp16
    f16*   outh  = Af;                                       // reuse after gemm_bs<0>
    f16*   Wvt   = Af + (size_t)MQ * 256;                    // 256*256
    f16*   Wot   = Wvt + 65536;
    f16*   Wch   = Wot + 65536;                              // 288*256
    float* bcat  = (float*)(Wch + 73728);

    dim3 blk(256);

    prep_feat<<<dim3(263, 8, 5), blk, 0, stream>>>(feat0, feat1, feat2,
                                                   W_val, W_out, W_off, W_attn,
                                                   b_off, b_attn,
                                                   Af, Wvt, Wot, Wch, bcat);
    gemm_bs<0><<<dim3(9, 263), blk, 0, stream>>>(query, Af, nullptr,
                                                 Wvt, Wch, Wot, b_val, bcat, b_out,
                                                 valh, rawo, attnh, nullptr);
    sample_v7<<<dim3(MQ / 8), blk, 0, stream>>>(valh, rawo, attnh, refp, outh);
    gemm_bs<1><<<dim3(4, 263), blk, 0, stream>>>(query, Af, outh,
                                                 Wvt, Wch, Wot, b_val, bcat, b_out,
                                                 nullptr, nullptr, nullptr, out);
}

// Round 5
// 241.214 us; speedup vs baseline: 1.0739x; 1.0739x over previous
//
#include <hip/hip_runtime.h>
#include <math.h>

#define NH    8
#define DIM   256
#define NQ    8400
#define BATCH 4
#define STOT  8400
#define MQ    (BATCH * NQ)   // 33600

typedef _Float16 f16;
typedef __attribute__((ext_vector_type(2))) _Float16 f16x2;
typedef __attribute__((ext_vector_type(8))) _Float16 f16x8;
typedef __attribute__((ext_vector_type(4))) float  f32x4;

// Async global->LDS, 16B per lane. LDS dest is wave-uniform base + lane*16.
static __device__ __forceinline__ void gl_lds16(const void* g, void* l) {
    __builtin_amdgcn_global_load_lds(
        (const __attribute__((address_space(1))) unsigned int*)g,
        (__attribute__((address_space(3))) unsigned int*)(unsigned int)(unsigned long long)l,
        16, 0, 0);
}

// ---------------------------------------------------------------------------
// Fused prep (r0 structure): z=0..3 feat transpose (3 levels concat) for batch
// z; z=4: weight transposes + bias concat; z=5: query fp32 -> fp16.
__global__ __launch_bounds__(256) void prep_all(
    const float* __restrict__ feat0, const float* __restrict__ feat1,
    const float* __restrict__ feat2, const float* __restrict__ query,
    const float* __restrict__ W_val, const float* __restrict__ W_out,
    const float* __restrict__ W_off, const float* __restrict__ W_attn,
    const float* __restrict__ b_off, const float* __restrict__ b_attn,
    f16* __restrict__ Af, f16* __restrict__ Qh,
    f16* __restrict__ Wvt, f16* __restrict__ Wot,
    f16* __restrict__ Wch, float* __restrict__ bcat)
{
    const int z = blockIdx.z;
    const int t = threadIdx.x;
    __shared__ float tile[32][33];
    const int c = t & 31, r = t >> 5;

    if (z == 5) {  // query conversion, 16 elems/thread
        size_t base = ((size_t)(blockIdx.x * 8 + blockIdx.y) * 256 + t) * 16;
        if (base < (size_t)MQ * 256) {
            #pragma unroll
            for (int i = 0; i < 2; ++i) {
                float4 q0 = *(const float4*)(query + base + i * 8);
                float4 q1 = *(const float4*)(query + base + i * 8 + 4);
                f16x8 hv;
                hv[0] = (f16)q0.x; hv[1] = (f16)q0.y; hv[2] = (f16)q0.z; hv[3] = (f16)q0.w;
                hv[4] = (f16)q1.x; hv[5] = (f16)q1.y; hv[6] = (f16)q1.z; hv[7] = (f16)q1.w;
                *(f16x8*)(Qh + base + i * 8) = hv;
            }
        }
        return;
    }

    if (z == 4) {
        const int xb = blockIdx.x;
        if (xb > 25) return;
        if (xb == 25) {
            if (blockIdx.y == 0)
                for (int i = t; i < 288; i += 256)
                    bcat[i] = (i < 192) ? b_off[i] : b_attn[i - 192];
            return;
        }
        const float* W; f16* oH; int Nw, n0, nb;
        if (xb < 8)       { W = W_val;  oH = Wvt; Nw = 256; n0 = 0;   nb = xb * 32; }
        else if (xb < 16) { W = W_out;  oH = Wot; Nw = 256; n0 = 0;   nb = (xb - 8) * 32; }
        else if (xb < 22) { W = W_off;  oH = Wch; Nw = 192; n0 = 0;   nb = (xb - 16) * 32; }
        else              { W = W_attn; oH = Wch; Nw = 96;  n0 = 192; nb = (xb - 22) * 32; }
        const int k0 = blockIdx.y * 32;
        #pragma unroll
        for (int i = 0; i < 4; ++i) {
            int k = k0 + r + i * 8, n = nb + c;
            tile[r + i * 8][c] = (n < Nw) ? W[(size_t)k * Nw + n] : 0.f;
        }
        __syncthreads();
        #pragma unroll
        for (int i = 0; i < 4; ++i) {
            int n = nb + r + i * 8, k = k0 + c;
            if (n < Nw)
                oH[(size_t)(n0 + n) * 256 + k] = (f16)tile[c][r + i * 8];
        }
        return;
    }

    const int b = z;
    const int s0 = blockIdx.x * 32, k0 = blockIdx.y * 32;
    if (s0 >= 8400) return;
    const float* f0b = feat0 + (size_t)b * 256 * 6400;
    const float* f1b = feat1 + (size_t)b * 256 * 1600;
    const float* f2b = feat2 + (size_t)b * 256 * 400;
    #pragma unroll
    for (int i = 0; i < 4; ++i) {
        int rr = r + i * 8;
        int s = s0 + c;
        float v = 0.f;
        if (s < 8400) {
            const float* fp; int S, sl;
            if (s < 6400)      { fp = f0b; S = 6400; sl = s; }
            else if (s < 8000) { fp = f1b; S = 1600; sl = s - 6400; }
            else               { fp = f2b; S = 400;  sl = s - 8000; }
            v = fp[(size_t)(k0 + rr) * S + sl];
        }
        tile[rr][c] = v;
    }
    __syncthreads();
    #pragma unroll
    for (int i = 0; i < 4; ++i) {
        int s = s0 + r + i * 8, k = k0 + c;
        if (s < 8400)
            Af[((size_t)b * 8400 + s) * 256 + k] = (f16)tile[c][r + i * 8];
    }
}

// ---------------------------------------------------------------------------
// m97-style GEMM core (r0 structure): global_load_lds(16B) staging into
// unpadded pitch-32 LDS with XOR chunk swizzle, tile 128x128, BK=32,
// mfma_f32_16x16x32_f16.  NEW vs r0: bijective XCD-chunk swizzle of the
// (bx,by) tile id so the 5 (or 2) blocks sharing one A-panel land on the SAME
// XCD's L2 (panel fetched ~1x instead of 5x); tanh applied in epilogue.
// KIND 0: fused val (lx<2) + raw (lx>=2).  KIND 1: out projection.
template<int KIND>
__global__ __launch_bounds__(256) void gemm_glds(
    const f16* __restrict__ A0, const f16* __restrict__ A1,
    const f16* __restrict__ B0, const f16* __restrict__ B1,
    const float* __restrict__ bias0, const float* __restrict__ bias1,
    f16* __restrict__ valh, float* __restrict__ rawo, f16* __restrict__ attnh,
    float* __restrict__ Cf)
{
    __shared__ f16 Ah[128 * 32];
    __shared__ f16 Bs[128 * 32];

    // ---- bijective XCD-chunk swizzle (m204): hw dispatch round-robins linear
    // bid across 8 XCDs; remap so consecutive logical tiles share an XCD.
    const int GX  = (KIND == 0) ? 5 : 2;
    const int nwg = GX * 263;
    const int bid = blockIdx.y * GX + blockIdx.x;
    const int qc = nwg >> 3, rc = nwg & 7;
    const int xcd = bid & 7, off = bid >> 3;
    const int wgid = (xcd < rc ? xcd * (qc + 1) : rc * (qc + 1) + (xcd - rc) * qc) + off;
    const int lx = wgid % GX, ly = wgid / GX;

    const bool split = (KIND == 0) && (lx >= 2);
    const int bn = split ? (lx - 2) * 128 : lx * 128;
    const int bm = ly * 128;
    const int N = split ? 288 : 256;
    const f16* Ag = split ? A1 : A0;
    const f16* Bg = split ? B1 : B0;
    const float* bias = split ? bias1 : bias0;

    const int t = threadIdx.x;
    const int lane = t & 63, w = t >> 6;
    const int wm = (w & 1) * 64, wn = (w >> 1) * 64;
    const int l15 = lane & 15, quad = lane >> 4;

    // staging constants: slot s = i*256 + t; row = i*64 + (t>>2); q' = t&3;
    // loaded k-chunk = q' ^ f(row), f independent of i.
    const int fstage = ((t >> 2) & 3) ^ ((t >> 4) & 3);
    const int qs = (t & 3) ^ fstage;
    // fragment k-chunk position: quad ^ f(row), f(row) = (l15&3)^((l15>>2)&3)
    const int ffrag = (l15 & 3) ^ ((l15 >> 2) & 3);
    const int qf = quad ^ ffrag;

    f32x4 acc[4][4];
    #pragma unroll
    for (int i = 0; i < 4; ++i)
        #pragma unroll
        for (int j = 0; j < 4; ++j)
            acc[i][j] = (f32x4){0.f, 0.f, 0.f, 0.f};

    for (int k0 = 0; k0 < 256; k0 += 32) {
        #pragma unroll
        for (int i = 0; i < 2; ++i) {
            int row = i * 64 + (t >> 2);
            int slot = i * 256 + t;
            int gr = bm + row; if (gr > MQ - 1) gr = MQ - 1;
            gl_lds16(Ag + (size_t)gr * 256 + k0 + qs * 8, &Ah[slot * 8]);
            int gn = bn + row; if (gn > N - 1) gn = N - 1;
            gl_lds16(Bg + (size_t)gn * 256 + k0 + qs * 8, &Bs[slot * 8]);
        }
        __syncthreads();

        f16x8 af[4], bfv[4];
        #pragma unroll
        for (int mt = 0; mt < 4; ++mt)
            af[mt] = *(const f16x8*)&Ah[((wm + mt * 16 + l15) * 4 + qf) * 8];
        #pragma unroll
        for (int nt = 0; nt < 4; ++nt)
            bfv[nt] = *(const f16x8*)&Bs[((wn + nt * 16 + l15) * 4 + qf) * 8];
        #pragma unroll
        for (int mt = 0; mt < 4; ++mt)
            #pragma unroll
            for (int nt = 0; nt < 4; ++nt)
                acc[mt][nt] = __builtin_amdgcn_mfma_f32_16x16x32_f16(af[mt], bfv[nt], acc[mt][nt], 0, 0, 0);
        __syncthreads();
    }

    #pragma unroll
    for (int nt = 0; nt < 4; ++nt) {
        int col = bn + wn + nt * 16 + l15;
        float bv = (col < N) ? bias[col] : 0.f;
        #pragma unroll
        for (int mt = 0; mt < 4; ++mt) {
            int row0 = bm + wm + mt * 16 + quad * 4;
            #pragma unroll
            for (int r = 0; r < 4; ++r) {
                int row = row0 + r;
                if (row >= MQ || col >= N) continue;
                float v = acc[mt][nt][r] + bv;
                if (KIND == 1) {
                    Cf[(size_t)row * 256 + col] = v;
                } else if (!split) {
                    int bb = row / STOT, s = row - bb * STOT;
                    int h = col >> 5, c = col & 31;
                    valh[(((size_t)(bb * 8 + h)) * STOT + s) * 32 + c] = (f16)v;
                } else if (col < 192) {
                    rawo[(size_t)row * 192 + col] = 0.5f * tanhf(v);  // tanh hoisted out of sampler
                } else {
                    attnh[(size_t)row * 96 + (col - 192)] = (f16)v;
                }
            }
        }
    }
}

// ---------------------------------------------------------------------------
// Sampler v7: packed (w16|idx16) LDS (12.8KB -> higher occupancy), tanh
// pre-applied upstream, packed-fp16 inner loop, fp32 flush per 12 corners.
__global__ __launch_bounds__(256) void sample_v7(
    const f16* __restrict__ valh,        // [B*8][STOT][32] fp16
    const float* __restrict__ off05,     // [MQ][192] = 0.5*tanh(raw) (fp32)
    const f16* __restrict__ attnh,       // [MQ][96] fp16
    const float* __restrict__ refp,      // [MQ][2]
    f16* __restrict__ out_h)             // [MQ][256] fp16
{
    const int bx = blockIdx.x;
    const int xcd = bx & 7;
    const int b = xcd >> 1;
    const int qi = (bx >> 3) * 2 + (xcd & 1);
    const int bq0 = b * NQ + qi * 8;
    const int t = threadIdx.x;

    __shared__ unsigned s_pk[8][96][4];   // (w16<<16)|idx16 per corner
    __shared__ float    s_m[8][8];
    __shared__ float    s_inv[8][8];

    if (t < 64) {
        int q = t >> 3, h = t & 7;
        const f16* a = attnh + (size_t)(bq0 + q) * 96 + h * 12;
        float m = (float)a[0];
        #pragma unroll
        for (int j = 1; j < 12; ++j) m = fmaxf(m, (float)a[j]);
        float s = 0.f;
        #pragma unroll
        for (int j = 0; j < 12; ++j) s += expf((float)a[j] - m);
        s_m[q][h] = m;
        s_inv[q][h] = 1.f / s;
    }
    __syncthreads();

    for (int i = t; i < 768; i += 256) {
        int q = i / 96, p = i - q * 96;
        int h = p / 12, lp = p - h * 12, l = lp >> 2;
        const int dims[3]   = {80, 40, 20};
        const int bases_[3] = {0, 6400, 8000};
        int Wl = dims[l], base = bases_[l];
        float logit = (float)attnh[(size_t)(bq0 + q) * 96 + p];
        float aw = expf(logit - s_m[q][h]) * s_inv[q][h];
        size_t ro = (size_t)(bq0 + q) * 192 + h * 24 + lp * 2;
        float ox = off05[ro], oy = off05[ro + 1];
        float rx = refp[(size_t)(bq0 + q) * 2];
        float ry = refp[(size_t)(bq0 + q) * 2 + 1];
        float ix = (rx + ox) * Wl - 0.5f;
        float iy = (ry + oy) * Wl - 0.5f;
        float x0f = floorf(ix), y0f = floorf(iy);
        float fx = ix - x0f, fy = iy - y0f;
        int x0 = (int)x0f, y0 = (int)y0f;
        float w00 = (1.f - fx) * (1.f - fy) * aw;
        float w01 = fx * (1.f - fy) * aw;
        float w10 = (1.f - fx) * fy * aw;
        float w11 = fx * fy * aw;
        bool vx0 = (unsigned)x0 < (unsigned)Wl;
        bool vx1 = (unsigned)(x0 + 1) < (unsigned)Wl;
        bool vy0 = (unsigned)y0 < (unsigned)Wl;
        bool vy1 = (unsigned)(y0 + 1) < (unsigned)Wl;
        int row0 = base + y0 * Wl, row1 = row0 + Wl;
        float ws[4] = { vx0 && vy0 ? w00 : 0.f, vx1 && vy0 ? w01 : 0.f,
                        vx0 && vy1 ? w10 : 0.f, vx1 && vy1 ? w11 : 0.f };
        int   is[4] = { vx0 && vy0 ? row0 + x0 : 0, vx1 && vy0 ? row0 + x0 + 1 : 0,
                        vx0 && vy1 ? row1 + x0 : 0, vx1 && vy1 ? row1 + x0 + 1 : 0 };
        #pragma unroll
        for (int k = 0; k < 4; ++k) {
            unsigned short us = __builtin_bit_cast(unsigned short, (f16)ws[k]);
            s_pk[q][p][k] = ((unsigned)us << 16) | (unsigned)is[k];
        }
    }
    __syncthreads();

    const int q = t >> 5;
    const int h = (t >> 2) & 7;
    const int l4 = t & 3;
    const uint4* vb4 = (const uint4*)(valh + (size_t)(b * 8 + h) * STOT * 32);
    const unsigned* pkp = &s_pk[q][h * 12][0];
    float accf[8] = {};
    #pragma unroll
    for (int pp = 0; pp < 4; ++pp) {
        unsigned pk[12]; uint4 v[12];
        #pragma unroll
        for (int k = 0; k < 12; ++k) pk[k] = pkp[pp * 12 + k];
        #pragma unroll
        for (int k = 0; k < 12; ++k) v[k] = vb4[(size_t)(pk[k] & 0xffffu) * 4 + l4];
        f16x2 a0 = (f16x2)(f16)0, a1 = a0, a2 = a0, a3 = a0;
        #pragma unroll
        for (int k = 0; k < 12; ++k) {
            // (w,w) from packed word via v_perm_b32 (bytes 2,3,2,3)
            f16x2 wv = __builtin_bit_cast(f16x2,
                        __builtin_amdgcn_perm(pk[k], pk[k], 0x03020302u));
            a0 += wv * __builtin_bit_cast(f16x2, v[k].x);
            a1 += wv * __builtin_bit_cast(f16x2, v[k].y);
            a2 += wv * __builtin_bit_cast(f16x2, v[k].z);
            a3 += wv * __builtin_bit_cast(f16x2, v[k].w);
        }
        accf[0] += (float)a0[0]; accf[1] += (float)a0[1];
        accf[2] += (float)a1[0]; accf[3] += (float)a1[1];
        accf[4] += (float)a2[0]; accf[5] += (float)a2[1];
        accf[6] += (float)a3[0]; accf[7] += (float)a3[1];
    }
    f16x8 ob;
    #pragma unroll
    for (int c = 0; c < 8; ++c) ob[c] = (f16)accf[c];
    *(f16x8*)(out_h + (size_t)(bq0 + q) * 256 + h * 32 + l4 * 8) = ob;
}

// ---------------------------------------------------------------------------
extern "C" void kernel_launch(void* const* d_in, const int* in_sizes, int n_in,
                              void* d_out, int out_size, void* d_ws, size_t ws_size,
                              hipStream_t stream)
{
    const float* query  = (const float*)d_in[0];
    const float* feat0  = (const float*)d_in[1];
    const float* feat1  = (const float*)d_in[2];
    const float* feat2  = (const float*)d_in[3];
    const float* refp   = (const float*)d_in[4];
    const float* W_off  = (const float*)d_in[5];
    const float* b_off  = (const float*)d_in[6];
    const float* W_attn = (const float*)d_in[7];
    const float* b_attn = (const float*)d_in[8];
    const float* W_val  = (const float*)d_in[9];
    const float* b_val  = (const float*)d_in[10];
    const float* W_out  = (const float*)d_in[11];
    const float* b_out  = (const float*)d_in[12];
    float* out = (float*)d_out;

    // workspace (~85 MB)
    f16*   valh  = (f16*)d_ws;                               // MQ*256 fp16
    float* rawo  = (float*)(valh + (size_t)MQ * 256);        // MQ*192 f32 (0.5*tanh)
    f16*   attnh = (f16*)(rawo + (size_t)MQ * 192);          // MQ*96 fp16
    f16*   Af    = attnh + (size_t)MQ * 96;                  // MQ*256 fp16
    f16*   outh  = Af;                                       // reuse after gemm<0>
    f16*   Qh    = Af + (size_t)MQ * 256;                    // MQ*256 fp16
    f16*   Wvt   = Qh + (size_t)MQ * 256;                    // 256*256
    f16*   Wot   = Wvt + 65536;
    f16*   Wch   = Wot + 65536;                              // 288*256
    float* bcat  = (float*)(Wch + 73728);

    dim3 blk(256);

    prep_all<<<dim3(263, 8, 6), blk, 0, stream>>>(feat0, feat1, feat2, query,
                                                  W_val, W_out, W_off, W_attn,
                                                  b_off, b_attn,
                                                  Af, Qh, Wvt, Wot, Wch, bcat);
    gemm_glds<0><<<dim3(5, 263), blk, 0, stream>>>(Af, Qh, Wvt, Wch, b_val, bcat,
                                                   valh, rawo, attnh, nullptr);
    sample_v7<<<dim3(MQ / 8), blk, 0, stream>>>(valh, rawo, attnh, refp, outh);
    gemm_glds<1><<<dim3(2, 263), blk, 0, stream>>>(outh, nullptr, Wot, nullptr,
                                                   b_out, nullptr,
                                                   nullptr, nullptr, nullptr, out);
}

// Round 6
// 237.967 us; speedup vs baseline: 1.0886x; 1.0136x over previous
//
#include <hip/hip_runtime.h>
#include <math.h>

#define NH    8
#define DIM   256
#define NQ    8400
#define BATCH 4
#define STOT  8400
#define MQ    (BATCH * NQ)   // 33600

typedef _Float16 f16;
typedef __attribute__((ext_vector_type(2))) _Float16 f16x2;
typedef __attribute__((ext_vector_type(8))) _Float16 f16x8;
typedef __attribute__((ext_vector_type(4))) float  f32x4;

// Async global->LDS, 16B per lane. LDS dest is wave-uniform base + lane*16.
static __device__ __forceinline__ void gl_lds16(const void* g, void* l) {
    __builtin_amdgcn_global_load_lds(
        (const __attribute__((address_space(1))) unsigned int*)g,
        (__attribute__((address_space(3))) unsigned int*)(unsigned int)(unsigned long long)l,
        16, 0, 0);
}

// ---------------------------------------------------------------------------
// Fused prep (r0 structure): z=0..3 feat transpose (3 levels concat) for batch
// z; z=4: weight transposes + bias concat; z=5: query fp32 -> fp16.
__global__ __launch_bounds__(256) void prep_all(
    const float* __restrict__ feat0, const float* __restrict__ feat1,
    const float* __restrict__ feat2, const float* __restrict__ query,
    const float* __restrict__ W_val, const float* __restrict__ W_out,
    const float* __restrict__ W_off, const float* __restrict__ W_attn,
    const float* __restrict__ b_off, const float* __restrict__ b_attn,
    f16* __restrict__ Af, f16* __restrict__ Qh,
    f16* __restrict__ Wvt, f16* __restrict__ Wot,
    f16* __restrict__ Wch, float* __restrict__ bcat)
{
    const int z = blockIdx.z;
    const int t = threadIdx.x;
    __shared__ float tile[32][33];
    const int c = t & 31, r = t >> 5;

    if (z == 5) {  // query conversion, 16 elems/thread
        size_t base = ((size_t)(blockIdx.x * 8 + blockIdx.y) * 256 + t) * 16;
        if (base < (size_t)MQ * 256) {
            #pragma unroll
            for (int i = 0; i < 2; ++i) {
                float4 q0 = *(const float4*)(query + base + i * 8);
                float4 q1 = *(const float4*)(query + base + i * 8 + 4);
                f16x8 hv;
                hv[0] = (f16)q0.x; hv[1] = (f16)q0.y; hv[2] = (f16)q0.z; hv[3] = (f16)q0.w;
                hv[4] = (f16)q1.x; hv[5] = (f16)q1.y; hv[6] = (f16)q1.z; hv[7] = (f16)q1.w;
                *(f16x8*)(Qh + base + i * 8) = hv;
            }
        }
        return;
    }

    if (z == 4) {
        const int xb = blockIdx.x;
        if (xb > 25) return;
        if (xb == 25) {
            if (blockIdx.y == 0)
                for (int i = t; i < 288; i += 256)
                    bcat[i] = (i < 192) ? b_off[i] : b_attn[i - 192];
            return;
        }
        const float* W; f16* oH; int Nw, n0, nb;
        if (xb < 8)       { W = W_val;  oH = Wvt; Nw = 256; n0 = 0;   nb = xb * 32; }
        else if (xb < 16) { W = W_out;  oH = Wot; Nw = 256; n0 = 0;   nb = (xb - 8) * 32; }
        else if (xb < 22) { W = W_off;  oH = Wch; Nw = 192; n0 = 0;   nb = (xb - 16) * 32; }
        else              { W = W_attn; oH = Wch; Nw = 96;  n0 = 192; nb = (xb - 22) * 32; }
        const int k0 = blockIdx.y * 32;
        #pragma unroll
        for (int i = 0; i < 4; ++i) {
            int k = k0 + r + i * 8, n = nb + c;
            tile[r + i * 8][c] = (n < Nw) ? W[(size_t)k * Nw + n] : 0.f;
        }
        __syncthreads();
        #pragma unroll
        for (int i = 0; i < 4; ++i) {
            int n = nb + r + i * 8, k = k0 + c;
            if (n < Nw)
                oH[(size_t)(n0 + n) * 256 + k] = (f16)tile[c][r + i * 8];
        }
        return;
    }

    const int b = z;
    const int s0 = blockIdx.x * 32, k0 = blockIdx.y * 32;
    if (s0 >= 8400) return;
    const float* f0b = feat0 + (size_t)b * 256 * 6400;
    const float* f1b = feat1 + (size_t)b * 256 * 1600;
    const float* f2b = feat2 + (size_t)b * 256 * 400;
    #pragma unroll
    for (int i = 0; i < 4; ++i) {
        int rr = r + i * 8;
        int s = s0 + c;
        float v = 0.f;
        if (s < 8400) {
            const float* fp; int S, sl;
            if (s < 6400)      { fp = f0b; S = 6400; sl = s; }
            else if (s < 8000) { fp = f1b; S = 1600; sl = s - 6400; }
            else               { fp = f2b; S = 400;  sl = s - 8000; }
            v = fp[(size_t)(k0 + rr) * S + sl];
        }
        tile[rr][c] = v;
    }
    __syncthreads();
    #pragma unroll
    for (int i = 0; i < 4; ++i) {
        int s = s0 + r + i * 8, k = k0 + c;
        if (s < 8400)
            Af[((size_t)b * 8400 + s) * 256 + k] = (f16)tile[c][r + i * 8];
    }
}

// ---------------------------------------------------------------------------
// m97-style GEMM core: global_load_lds(16B) staging into unpadded pitch-32
// LDS with XOR chunk swizzle, tile 128x128, BK=32, mfma_f32_16x16x32_f16.
// Bijective XCD-chunk swizzle (m204) so blocks sharing an A-panel share an
// XCD L2; tanh applied in epilogue.
// KIND 0: fused val (lx<2) + raw (lx>=2).  KIND 1: out projection.
template<int KIND>
__global__ __launch_bounds__(256) void gemm_glds(
    const f16* __restrict__ A0, const f16* __restrict__ A1,
    const f16* __restrict__ B0, const f16* __restrict__ B1,
    const float* __restrict__ bias0, const float* __restrict__ bias1,
    f16* __restrict__ valh, float* __restrict__ rawo, f16* __restrict__ attnh,
    float* __restrict__ Cf)
{
    __shared__ f16 Ah[128 * 32];
    __shared__ f16 Bs[128 * 32];

    const int GX  = (KIND == 0) ? 5 : 2;
    const int nwg = GX * 263;
    const int bid = blockIdx.y * GX + blockIdx.x;
    const int qc = nwg >> 3, rc = nwg & 7;
    const int xcd = bid & 7, off = bid >> 3;
    const int wgid = (xcd < rc ? xcd * (qc + 1) : rc * (qc + 1) + (xcd - rc) * qc) + off;
    const int lx = wgid % GX, ly = wgid / GX;

    const bool split = (KIND == 0) && (lx >= 2);
    const int bn = split ? (lx - 2) * 128 : lx * 128;
    const int bm = ly * 128;
    const int N = split ? 288 : 256;
    const f16* Ag = split ? A1 : A0;
    const f16* Bg = split ? B1 : B0;
    const float* bias = split ? bias1 : bias0;

    const int t = threadIdx.x;
    const int lane = t & 63, w = t >> 6;
    const int wm = (w & 1) * 64, wn = (w >> 1) * 64;
    const int l15 = lane & 15, quad = lane >> 4;

    const int fstage = ((t >> 2) & 3) ^ ((t >> 4) & 3);
    const int qs = (t & 3) ^ fstage;
    const int ffrag = (l15 & 3) ^ ((l15 >> 2) & 3);
    const int qf = quad ^ ffrag;

    f32x4 acc[4][4];
    #pragma unroll
    for (int i = 0; i < 4; ++i)
        #pragma unroll
        for (int j = 0; j < 4; ++j)
            acc[i][j] = (f32x4){0.f, 0.f, 0.f, 0.f};

    for (int k0 = 0; k0 < 256; k0 += 32) {
        #pragma unroll
        for (int i = 0; i < 2; ++i) {
            int row = i * 64 + (t >> 2);
            int slot = i * 256 + t;
            int gr = bm + row; if (gr > MQ - 1) gr = MQ - 1;
            gl_lds16(Ag + (size_t)gr * 256 + k0 + qs * 8, &Ah[slot * 8]);
            int gn = bn + row; if (gn > N - 1) gn = N - 1;
            gl_lds16(Bg + (size_t)gn * 256 + k0 + qs * 8, &Bs[slot * 8]);
        }
        __syncthreads();

        f16x8 af[4], bfv[4];
        #pragma unroll
        for (int mt = 0; mt < 4; ++mt)
            af[mt] = *(const f16x8*)&Ah[((wm + mt * 16 + l15) * 4 + qf) * 8];
        #pragma unroll
        for (int nt = 0; nt < 4; ++nt)
            bfv[nt] = *(const f16x8*)&Bs[((wn + nt * 16 + l15) * 4 + qf) * 8];
        #pragma unroll
        for (int mt = 0; mt < 4; ++mt)
            #pragma unroll
            for (int nt = 0; nt < 4; ++nt)
                acc[mt][nt] = __builtin_amdgcn_mfma_f32_16x16x32_f16(af[mt], bfv[nt], acc[mt][nt], 0, 0, 0);
        __syncthreads();
    }

    #pragma unroll
    for (int nt = 0; nt < 4; ++nt) {
        int col = bn + wn + nt * 16 + l15;
        float bv = (col < N) ? bias[col] : 0.f;
        #pragma unroll
        for (int mt = 0; mt < 4; ++mt) {
            int row0 = bm + wm + mt * 16 + quad * 4;
            #pragma unroll
            for (int r = 0; r < 4; ++r) {
                int row = row0 + r;
                if (row >= MQ || col >= N) continue;
                float v = acc[mt][nt][r] + bv;
                if (KIND == 1) {
                    Cf[(size_t)row * 256 + col] = v;
                } else if (!split) {
                    int bb = row / STOT, s = row - bb * STOT;
                    int h = col >> 5, c = col & 31;
                    valh[(((size_t)(bb * 8 + h)) * STOT + s) * 32 + c] = (f16)v;
                } else if (col < 192) {
                    rawo[(size_t)row * 192 + col] = 0.5f * tanhf(v);  // tanh hoisted out of sampler
                } else {
                    attnh[(size_t)row * 96 + (col - 192)] = (f16)v;
                }
            }
        }
    }
}

// ---------------------------------------------------------------------------
// Sampler v8: like v7 (packed (w16|idx16) LDS, tanh upstream) but the gather
// loop is an explicitly double-buffered pipeline: groups of 6 corners,
// ping-pong register buffers (statically indexed), next group's 6 gathers
// issued before current group's FMAs. __launch_bounds__(256,4) = 128-VGPR cap
// so the allocator keeps the in-flight loads live (v7 was strangled at 32
// VGPR -> ~3 outstanding gathers). Flush cadence 12 corners per fp32 flush,
// numerics identical to v7.
__global__ __launch_bounds__(256, 4) void sample_v8(
    const f16* __restrict__ valh,        // [B*8][STOT][32] fp16
    const float* __restrict__ off05,     // [MQ][192] = 0.5*tanh(raw) (fp32)
    const f16* __restrict__ attnh,       // [MQ][96] fp16
    const float* __restrict__ refp,      // [MQ][2]
    f16* __restrict__ out_h)             // [MQ][256] fp16
{
    const int bx = blockIdx.x;
    const int xcd = bx & 7;
    const int b = xcd >> 1;
    const int qi = (bx >> 3) * 2 + (xcd & 1);
    const int bq0 = b * NQ + qi * 8;
    const int t = threadIdx.x;

    __shared__ unsigned s_pk[8][96][4];   // (w16<<16)|idx16 per corner
    __shared__ float    s_m[8][8];
    __shared__ float    s_inv[8][8];

    if (t < 64) {
        int q = t >> 3, h = t & 7;
        const f16* a = attnh + (size_t)(bq0 + q) * 96 + h * 12;
        float m = (float)a[0];
        #pragma unroll
        for (int j = 1; j < 12; ++j) m = fmaxf(m, (float)a[j]);
        float s = 0.f;
        #pragma unroll
        for (int j = 0; j < 12; ++j) s += expf((float)a[j] - m);
        s_m[q][h] = m;
        s_inv[q][h] = 1.f / s;
    }
    __syncthreads();

    for (int i = t; i < 768; i += 256) {
        int q = i / 96, p = i - q * 96;
        int h = p / 12, lp = p - h * 12, l = lp >> 2;
        const int dims[3]   = {80, 40, 20};
        const int bases_[3] = {0, 6400, 8000};
        int Wl = dims[l], base = bases_[l];
        float logit = (float)attnh[(size_t)(bq0 + q) * 96 + p];
        float aw = expf(logit - s_m[q][h]) * s_inv[q][h];
        size_t ro = (size_t)(bq0 + q) * 192 + h * 24 + lp * 2;
        float ox = off05[ro], oy = off05[ro + 1];
        float rx = refp[(size_t)(bq0 + q) * 2];
        float ry = refp[(size_t)(bq0 + q) * 2 + 1];
        float ix = (rx + ox) * Wl - 0.5f;
        float iy = (ry + oy) * Wl - 0.5f;
        float x0f = floorf(ix), y0f = floorf(iy);
        float fx = ix - x0f, fy = iy - y0f;
        int x0 = (int)x0f, y0 = (int)y0f;
        float w00 = (1.f - fx) * (1.f - fy) * aw;
        float w01 = fx * (1.f - fy) * aw;
        float w10 = (1.f - fx) * fy * aw;
        float w11 = fx * fy * aw;
        bool vx0 = (unsigned)x0 < (unsigned)Wl;
        bool vx1 = (unsigned)(x0 + 1) < (unsigned)Wl;
        bool vy0 = (unsigned)y0 < (unsigned)Wl;
        bool vy1 = (unsigned)(y0 + 1) < (unsigned)Wl;
        int row0 = base + y0 * Wl, row1 = row0 + Wl;
        float ws[4] = { vx0 && vy0 ? w00 : 0.f, vx1 && vy0 ? w01 : 0.f,
                        vx0 && vy1 ? w10 : 0.f, vx1 && vy1 ? w11 : 0.f };
        int   is[4] = { vx0 && vy0 ? row0 + x0 : 0, vx1 && vy0 ? row0 + x0 + 1 : 0,
                        vx0 && vy1 ? row1 + x0 : 0, vx1 && vy1 ? row1 + x0 + 1 : 0 };
        #pragma unroll
        for (int k = 0; k < 4; ++k) {
            unsigned short us = __builtin_bit_cast(unsigned short, (f16)ws[k]);
            s_pk[q][p][k] = ((unsigned)us << 16) | (unsigned)is[k];
        }
    }
    __syncthreads();

    const int q = t >> 5;
    const int h = (t >> 2) & 7;
    const int l4 = t & 3;
    const uint4* vb4 = (const uint4*)(valh + (size_t)(b * 8 + h) * STOT * 32);
    const unsigned* pkp = &s_pk[q][h * 12][0];
    float accf[8] = {};

    // double-buffered gather pipeline: 8 groups of 6 corners
    unsigned wk[2][6]; uint4 va[2][6];
    #pragma unroll
    for (int k = 0; k < 6; ++k) {
        unsigned p = pkp[k];
        wk[0][k] = p;
        va[0][k] = vb4[(size_t)(p & 0xffffu) * 4 + l4];
    }
    f16x2 a0 = (f16x2)(f16)0, a1 = a0, a2 = a0, a3 = a0;
    #pragma unroll
    for (int g = 0; g < 8; ++g) {
        const int cur = g & 1, nxt = cur ^ 1;
        if (g < 7) {
            #pragma unroll
            for (int k = 0; k < 6; ++k) {
                unsigned p = pkp[(g + 1) * 6 + k];
                wk[nxt][k] = p;
                va[nxt][k] = vb4[(size_t)(p & 0xffffu) * 4 + l4];
            }
        }
        if ((g & 1) == 0) { a0 = (f16x2)(f16)0; a1 = a0; a2 = a0; a3 = a0; }
        #pragma unroll
        for (int k = 0; k < 6; ++k) {
            f16x2 wv = __builtin_bit_cast(f16x2,
                        __builtin_amdgcn_perm(wk[cur][k], wk[cur][k], 0x03020302u));
            a0 += wv * __builtin_bit_cast(f16x2, va[cur][k].x);
            a1 += wv * __builtin_bit_cast(f16x2, va[cur][k].y);
            a2 += wv * __builtin_bit_cast(f16x2, va[cur][k].z);
            a3 += wv * __builtin_bit_cast(f16x2, va[cur][k].w);
        }
        if (g & 1) {   // flush every 12 corners (same cadence/order as v7)
            accf[0] += (float)a0[0]; accf[1] += (float)a0[1];
            accf[2] += (float)a1[0]; accf[3] += (float)a1[1];
            accf[4] += (float)a2[0]; accf[5] += (float)a2[1];
            accf[6] += (float)a3[0]; accf[7] += (float)a3[1];
        }
    }
    f16x8 ob;
    #pragma unroll
    for (int c = 0; c < 8; ++c) ob[c] = (f16)accf[c];
    *(f16x8*)(out_h + (size_t)(bq0 + q) * 256 + h * 32 + l4 * 8) = ob;
}

// ---------------------------------------------------------------------------
extern "C" void kernel_launch(void* const* d_in, const int* in_sizes, int n_in,
                              void* d_out, int out_size, void* d_ws, size_t ws_size,
                              hipStream_t stream)
{
    const float* query  = (const float*)d_in[0];
    const float* feat0  = (const float*)d_in[1];
    const float* feat1  = (const float*)d_in[2];
    const float* feat2  = (const float*)d_in[3];
    const float* refp   = (const float*)d_in[4];
    const float* W_off  = (const float*)d_in[5];
    const float* b_off  = (const float*)d_in[6];
    const float* W_attn = (const float*)d_in[7];
    const float* b_attn = (const float*)d_in[8];
    const float* W_val  = (const float*)d_in[9];
    const float* b_val  = (const float*)d_in[10];
    const float* W_out  = (const float*)d_in[11];
    const float* b_out  = (const float*)d_in[12];
    float* out = (float*)d_out;

    // workspace (~85 MB)
    f16*   valh  = (f16*)d_ws;                               // MQ*256 fp16
    float* rawo  = (float*)(valh + (size_t)MQ * 256);        // MQ*192 f32 (0.5*tanh)
    f16*   attnh = (f16*)(rawo + (size_t)MQ * 192);          // MQ*96 fp16
    f16*   Af    = attnh + (size_t)MQ * 96;                  // MQ*256 fp16
    f16*   outh  = Af;                                       // reuse after gemm<0>
    f16*   Qh    = Af + (size_t)MQ * 256;                    // MQ*256 fp16
    f16*   Wvt   = Qh + (size_t)MQ * 256;                    // 256*256
    f16*   Wot   = Wvt + 65536;
    f16*   Wch   = Wot + 65536;                              // 288*256
    float* bcat  = (float*)(Wch + 73728);

    dim3 blk(256);

    prep_all<<<dim3(263, 8, 6), blk, 0, stream>>>(feat0, feat1, feat2, query,
                                                  W_val, W_out, W_off, W_attn,
                                                  b_off, b_attn,
                                                  Af, Qh, Wvt, Wot, Wch, bcat);
    gemm_glds<0><<<dim3(5, 263), blk, 0, stream>>>(Af, Qh, Wvt, Wch, b_val, bcat,
                                                   valh, rawo, attnh, nullptr);
    sample_v8<<<dim3(MQ / 8), blk, 0, stream>>>(valh, rawo, attnh, refp, outh);
    gemm_glds<1><<<dim3(2, 263), blk, 0, stream>>>(outh, nullptr, Wot, nullptr,
                                                   b_out, nullptr,
                                                   nullptr, nullptr, nullptr, out);
}

// Round 9
// 237.699 us; speedup vs baseline: 1.0898x; 1.0011x over previous
//
#include <hip/hip_runtime.h>
#include <math.h>

#define NH    8
#define DIM   256
#define NQ    8400
#define BATCH 4
#define STOT  8400
#define MQ    (BATCH * NQ)   // 33600

typedef _Float16 f16;
typedef __attribute__((ext_vector_type(2))) _Float16 f16x2;
typedef __attribute__((ext_vector_type(8))) _Float16 f16x8;
typedef __attribute__((ext_vector_type(4))) float  f32x4;

// Async global->LDS, 16B per lane. LDS dest is wave-uniform base + lane*16.
static __device__ __forceinline__ void gl_lds16(const void* g, void* l) {
    __builtin_amdgcn_global_load_lds(
        (const __attribute__((address_space(1))) unsigned int*)g,
        (__attribute__((address_space(3))) unsigned int*)(unsigned int)(unsigned long long)l,
        16, 0, 0);
}

// ---------------------------------------------------------------------------
// prep_all v2: z=0..3 feat transpose+cvt with float4 loads (64s x 32k tiles);
// z=4: weight transposes + bias concat; z=5: query fp32->fp16, 32 elems/thread.
__global__ __launch_bounds__(256) void prep_all(
    const float* __restrict__ feat0, const float* __restrict__ feat1,
    const float* __restrict__ feat2, const float* __restrict__ query,
    const float* __restrict__ W_val, const float* __restrict__ W_out,
    const float* __restrict__ W_off, const float* __restrict__ W_attn,
    const float* __restrict__ b_off, const float* __restrict__ b_attn,
    f16* __restrict__ Af, f16* __restrict__ Qh,
    f16* __restrict__ Wvt, f16* __restrict__ Wot,
    f16* __restrict__ Wch, float* __restrict__ bcat)
{
    const int z = blockIdx.z;
    const int t = threadIdx.x;
    __shared__ float tile[32][68];

    if (z == 5) {  // query conversion, 32 elems/thread, exact 1050-block cover
        int blk = blockIdx.x * 8 + blockIdx.y;
        if (blk >= 1050) return;
        size_t base = ((size_t)blk * 256 + t) * 32;
        #pragma unroll
        for (int i = 0; i < 4; ++i) {
            float4 q0 = *(const float4*)(query + base + i * 8);
            float4 q1 = *(const float4*)(query + base + i * 8 + 4);
            f16x8 hv;
            hv[0] = (f16)q0.x; hv[1] = (f16)q0.y; hv[2] = (f16)q0.z; hv[3] = (f16)q0.w;
            hv[4] = (f16)q1.x; hv[5] = (f16)q1.y; hv[6] = (f16)q1.z; hv[7] = (f16)q1.w;
            *(f16x8*)(Qh + base + i * 8) = hv;
        }
        return;
    }

    if (z == 4) {
        const int xb = blockIdx.x;
        const int c = t & 31, r = t >> 5;
        if (xb > 25) return;
        if (xb == 25) {
            if (blockIdx.y == 0)
                for (int i = t; i < 288; i += 256)
                    bcat[i] = (i < 192) ? b_off[i] : b_attn[i - 192];
            return;
        }
        const float* W; f16* oH; int Nw, n0, nb;
        if (xb < 8)       { W = W_val;  oH = Wvt; Nw = 256; n0 = 0;   nb = xb * 32; }
        else if (xb < 16) { W = W_out;  oH = Wot; Nw = 256; n0 = 0;   nb = (xb - 8) * 32; }
        else if (xb < 22) { W = W_off;  oH = Wch; Nw = 192; n0 = 0;   nb = (xb - 16) * 32; }
        else              { W = W_attn; oH = Wch; Nw = 96;  n0 = 192; nb = (xb - 22) * 32; }
        const int k0 = blockIdx.y * 32;
        #pragma unroll
        for (int i = 0; i < 4; ++i) {
            int k = k0 + r + i * 8, n = nb + c;
            tile[r + i * 8][c] = (n < Nw) ? W[(size_t)k * Nw + n] : 0.f;
        }
        __syncthreads();
        #pragma unroll
        for (int i = 0; i < 4; ++i) {
            int n = nb + r + i * 8, k = k0 + c;
            if (n < Nw)
                oH[(size_t)(n0 + n) * 256 + k] = (f16)tile[c][r + i * 8];
        }
        return;
    }

    // ---- feat transpose: tile = 64 s x 32 k, float4 loads along s
    // (level boundaries 6400/8000/8400 are 4-aligned: no float4 straddle)
    const int b = z;
    const int s0 = blockIdx.x * 64, k0 = blockIdx.y * 32;
    const float* f0b = feat0 + (size_t)b * 256 * 6400;
    const float* f1b = feat1 + (size_t)b * 256 * 1600;
    const float* f2b = feat2 + (size_t)b * 256 * 400;
    {
        const int c = t & 15, r = t >> 4;       // c: s-group (4 floats), r: k-row
        const int s4 = s0 + c * 4;
        const float* fp; int S, sl;
        bool ok = (s4 < 8400);
        if (s4 < 6400)      { fp = f0b; S = 6400; sl = s4; }
        else if (s4 < 8000) { fp = f1b; S = 1600; sl = s4 - 6400; }
        else                { fp = f2b; S = 400;  sl = s4 - 8000; }
        #pragma unroll
        for (int i = 0; i < 2; ++i) {
            int kr = r + i * 16;
            float4 v = ok ? *(const float4*)(fp + (size_t)(k0 + kr) * S + sl)
                          : (float4){0.f, 0.f, 0.f, 0.f};
            *(float4*)&tile[kr][c * 4] = v;
        }
    }
    __syncthreads();
    {
        const int s_local = t >> 2, kq = t & 3;   // 64 s-rows, 4 k-chunks of 8
        if (s0 + s_local < 8400) {
            f16x8 h;
            #pragma unroll
            for (int j = 0; j < 8; ++j)
                h[j] = (f16)tile[kq * 8 + j][s_local];
            *(f16x8*)(Af + ((size_t)b * 8400 + s0 + s_local) * 256 + k0 + kq * 8) = h;
        }
    }
}

// ---------------------------------------------------------------------------
// m97-style GEMM core (r6): global_load_lds(16B) staging into unpadded
// pitch-32 LDS with XOR chunk swizzle, tile 128x128, BK=32, 16x16x32 MFMA.
// Bijective XCD-chunk swizzle (m204); tanh applied in epilogue.
// KIND 0: fused val (lx<2) + raw (lx>=2).  KIND 1: out projection.
template<int KIND>
__global__ __launch_bounds__(256) void gemm_glds(
    const f16* __restrict__ A0, const f16* __restrict__ A1,
    const f16* __restrict__ B0, const f16* __restrict__ B1,
    const float* __restrict__ bias0, const float* __restrict__ bias1,
    f16* __restrict__ valh, float* __restrict__ rawo, f16* __restrict__ attnh,
    float* __restrict__ Cf)
{
    __shared__ f16 Ah[128 * 32];
    __shared__ f16 Bs[128 * 32];

    const int GX  = (KIND == 0) ? 5 : 2;
    const int nwg = GX * 263;
    const int bid = blockIdx.y * GX + blockIdx.x;
    const int qc = nwg >> 3, rc = nwg & 7;
    const int xcd = bid & 7, off = bid >> 3;
    const int wgid = (xcd < rc ? xcd * (qc + 1) : rc * (qc + 1) + (xcd - rc) * qc) + off;
    const int lx = wgid % GX, ly = wgid / GX;

    const bool split = (KIND == 0) && (lx >= 2);
    const int bn = split ? (lx - 2) * 128 : lx * 128;
    const int bm = ly * 128;
    const int N = split ? 288 : 256;
    const f16* Ag = split ? A1 : A0;
    const f16* Bg = split ? B1 : B0;
    const float* bias = split ? bias1 : bias0;

    const int t = threadIdx.x;
    const int lane = t & 63, w = t >> 6;
    const int wm = (w & 1) * 64, wn = (w >> 1) * 64;
    const int l15 = lane & 15, quad = lane >> 4;

    const int fstage = ((t >> 2) & 3) ^ ((t >> 4) & 3);
    const int qs = (t & 3) ^ fstage;
    const int ffrag = (l15 & 3) ^ ((l15 >> 2) & 3);
    const int qf = quad ^ ffrag;

    f32x4 acc[4][4];
    #pragma unroll
    for (int i = 0; i < 4; ++i)
        #pragma unroll
        for (int j = 0; j < 4; ++j)
            acc[i][j] = (f32x4){0.f, 0.f, 0.f, 0.f};

    for (int k0 = 0; k0 < 256; k0 += 32) {
        #pragma unroll
        for (int i = 0; i < 2; ++i) {
            int row = i * 64 + (t >> 2);
            int slot = i * 256 + t;
            int gr = bm + row; if (gr > MQ - 1) gr = MQ - 1;
            gl_lds16(Ag + (size_t)gr * 256 + k0 + qs * 8, &Ah[slot * 8]);
            int gn = bn + row; if (gn > N - 1) gn = N - 1;
            gl_lds16(Bg + (size_t)gn * 256 + k0 + qs * 8, &Bs[slot * 8]);
        }
        __syncthreads();

        f16x8 af[4], bfv[4];
        #pragma unroll
        for (int mt = 0; mt < 4; ++mt)
            af[mt] = *(const f16x8*)&Ah[((wm + mt * 16 + l15) * 4 + qf) * 8];
        #pragma unroll
        for (int nt = 0; nt < 4; ++nt)
            bfv[nt] = *(const f16x8*)&Bs[((wn + nt * 16 + l15) * 4 + qf) * 8];
        #pragma unroll
        for (int mt = 0; mt < 4; ++mt)
            #pragma unroll
            for (int nt = 0; nt < 4; ++nt)
                acc[mt][nt] = __builtin_amdgcn_mfma_f32_16x16x32_f16(af[mt], bfv[nt], acc[mt][nt], 0, 0, 0);
        __syncthreads();
    }

    #pragma unroll
    for (int nt = 0; nt < 4; ++nt) {
        int col = bn + wn + nt * 16 + l15;
        float bv = (col < N) ? bias[col] : 0.f;
        #pragma unroll
        for (int mt = 0; mt < 4; ++mt) {
            int row0 = bm + wm + mt * 16 + quad * 4;
            #pragma unroll
            for (int r = 0; r < 4; ++r) {
                int row = row0 + r;
                if (row >= MQ || col >= N) continue;
                float v = acc[mt][nt][r] + bv;
                if (KIND == 1) {
                    Cf[(size_t)row * 256 + col] = v;
                } else if (!split) {
                    int bb = row / STOT, s = row - bb * STOT;
                    int h = col >> 5, c = col & 31;
                    valh[(((size_t)(bb * 8 + h)) * STOT + s) * 32 + c] = (f16)v;
                } else if (col < 192) {
                    rawo[(size_t)row * 192 + col] = 0.5f * tanhf(v);  // tanh hoisted out of sampler
                } else {
                    attnh[(size_t)row * 96 + (col - 192)] = (f16)v;
                }
            }
        }
    }
}

// ---------------------------------------------------------------------------
// Sampler v8b: exactly the r6 v8 code (proven correct, 52us) plus
// amdgpu_waves_per_eu(2,8): relaxing the minimum occupancy to 2 waves/EU
// raises the scheduler's VGPR budget (~256), removing the register-pressure
// trigger that made it sink all gathers to their uses (r6: VGPR_Count=32,
// ~3 loads in flight). The source-level ping-pong (12 issued ahead) can then
// survive into the ISA. Pure scheduling hint; no correctness surface.
__global__ __launch_bounds__(256)
__attribute__((amdgpu_waves_per_eu(2, 8)))
void sample_v8(
    const f16* __restrict__ valh,        // [B*8][STOT][32] fp16
    const float* __restrict__ off05,     // [MQ][192] = 0.5*tanh(raw) (fp32)
    const f16* __restrict__ attnh,       // [MQ][96] fp16
    const float* __restrict__ refp,      // [MQ][2]
    f16* __restrict__ out_h)             // [MQ][256] fp16
{
    const int bx = blockIdx.x;
    const int xcd = bx & 7;
    const int b = xcd >> 1;
    const int qi = (bx >> 3) * 2 + (xcd & 1);
    const int bq0 = b * NQ + qi * 8;
    const int t = threadIdx.x;

    __shared__ unsigned s_pk[8][96][4];   // (w16<<16)|idx16 per corner
    __shared__ float    s_m[8][8];
    __shared__ float    s_inv[8][8];

    if (t < 64) {
        int q = t >> 3, h = t & 7;
        const f16* a = attnh + (size_t)(bq0 + q) * 96 + h * 12;
        float m = (float)a[0];
        #pragma unroll
        for (int j = 1; j < 12; ++j) m = fmaxf(m, (float)a[j]);
        float s = 0.f;
        #pragma unroll
        for (int j = 0; j < 12; ++j) s += expf((float)a[j] - m);
        s_m[q][h] = m;
        s_inv[q][h] = 1.f / s;
    }
    __syncthreads();

    for (int i = t; i < 768; i += 256) {
        int q = i / 96, p = i - q * 96;
        int h = p / 12, lp = p - h * 12, l = lp >> 2;
        const int dims[3]   = {80, 40, 20};
        const int bases_[3] = {0, 6400, 8000};
        int Wl = dims[l], base = bases_[l];
        float logit = (float)attnh[(size_t)(bq0 + q) * 96 + p];
        float aw = expf(logit - s_m[q][h]) * s_inv[q][h];
        size_t ro = (size_t)(bq0 + q) * 192 + h * 24 + lp * 2;
        float ox = off05[ro], oy = off05[ro + 1];
        float rx = refp[(size_t)(bq0 + q) * 2];
        float ry = refp[(size_t)(bq0 + q) * 2 + 1];
        float ix = (rx + ox) * Wl - 0.5f;
        float iy = (ry + oy) * Wl - 0.5f;
        float x0f = floorf(ix), y0f = floorf(iy);
        float fx = ix - x0f, fy = iy - y0f;
        int x0 = (int)x0f, y0 = (int)y0f;
        float w00 = (1.f - fx) * (1.f - fy) * aw;
        float w01 = fx * (1.f - fy) * aw;
        float w10 = (1.f - fx) * fy * aw;
        float w11 = fx * fy * aw;
        bool vx0 = (unsigned)x0 < (unsigned)Wl;
        bool vx1 = (unsigned)(x0 + 1) < (unsigned)Wl;
        bool vy0 = (unsigned)y0 < (unsigned)Wl;
        bool vy1 = (unsigned)(y0 + 1) < (unsigned)Wl;
        int row0 = base + y0 * Wl, row1 = row0 + Wl;
        float ws[4] = { vx0 && vy0 ? w00 : 0.f, vx1 && vy0 ? w01 : 0.f,
                        vx0 && vy1 ? w10 : 0.f, vx1 && vy1 ? w11 : 0.f };
        int   is[4] = { vx0 && vy0 ? row0 + x0 : 0, vx1 && vy0 ? row0 + x0 + 1 : 0,
                        vx0 && vy1 ? row1 + x0 : 0, vx1 && vy1 ? row1 + x0 + 1 : 0 };
        #pragma unroll
        for (int k = 0; k < 4; ++k) {
            unsigned short us = __builtin_bit_cast(unsigned short, (f16)ws[k]);
            s_pk[q][p][k] = ((unsigned)us << 16) | (unsigned)is[k];
        }
    }
    __syncthreads();

    const int q = t >> 5;
    const int h = (t >> 2) & 7;
    const int l4 = t & 3;
    const uint4* vb4 = (const uint4*)(valh + (size_t)(b * 8 + h) * STOT * 32);
    const unsigned* pkp = &s_pk[q][h * 12][0];
    float accf[8] = {};

    // double-buffered gather pipeline: 8 groups of 6 corners
    unsigned wk[2][6]; uint4 va[2][6];
    #pragma unroll
    for (int k = 0; k < 6; ++k) {
        unsigned p = pkp[k];
        wk[0][k] = p;
        va[0][k] = vb4[(size_t)(p & 0xffffu) * 4 + l4];
    }
    f16x2 a0 = (f16x2)(f16)0, a1 = a0, a2 = a0, a3 = a0;
    #pragma unroll
    for (int g = 0; g < 8; ++g) {
        const int cur = g & 1, nxt = cur ^ 1;
        if (g < 7) {
            #pragma unroll
            for (int k = 0; k < 6; ++k) {
                unsigned p = pkp[(g + 1) * 6 + k];
                wk[nxt][k] = p;
                va[nxt][k] = vb4[(size_t)(p & 0xffffu) * 4 + l4];
            }
        }
        if ((g & 1) == 0) { a0 = (f16x2)(f16)0; a1 = a0; a2 = a0; a3 = a0; }
        #pragma unroll
        for (int k = 0; k < 6; ++k) {
            f16x2 wv = __builtin_bit_cast(f16x2,
                        __builtin_amdgcn_perm(wk[cur][k], wk[cur][k], 0x03020302u));
            a0 += wv * __builtin_bit_cast(f16x2, va[cur][k].x);
            a1 += wv * __builtin_bit_cast(f16x2, va[cur][k].y);
            a2 += wv * __builtin_bit_cast(f16x2, va[cur][k].z);
            a3 += wv * __builtin_bit_cast(f16x2, va[cur][k].w);
        }
        if (g & 1) {   // flush every 12 corners (same cadence/order as v7)
            accf[0] += (float)a0[0]; accf[1] += (float)a0[1];
            accf[2] += (float)a1[0]; accf[3] += (float)a1[1];
            accf[4] += (float)a2[0]; accf[5] += (float)a2[1];
            accf[6] += (float)a3[0]; accf[7] += (float)a3[1];
        }
    }
    f16x8 ob;
    #pragma unroll
    for (int c = 0; c < 8; ++c) ob[c] = (f16)accf[c];
    *(f16x8*)(out_h + (size_t)(bq0 + q) * 256 + h * 32 + l4 * 8) = ob;
}

// ---------------------------------------------------------------------------
extern "C" void kernel_launch(void* const* d_in, const int* in_sizes, int n_in,
                              void* d_out, int out_size, void* d_ws, size_t ws_size,
                              hipStream_t stream)
{
    const float* query  = (const float*)d_in[0];
    const float* feat0  = (const float*)d_in[1];
    const float* feat1  = (const float*)d_in[2];
    const float* feat2  = (const float*)d_in[3];
    const float* refp   = (const float*)d_in[4];
    const float* W_off  = (const float*)d_in[5];
    const float* b_off  = (const float*)d_in[6];
    const float* W_attn = (const float*)d_in[7];
    const float* b_attn = (const float*)d_in[8];
    const float* W_val  = (const float*)d_in[9];
    const float* b_val  = (const float*)d_in[10];
    const float* W_out  = (const float*)d_in[11];
    const float* b_out  = (const float*)d_in[12];
    float* out = (float*)d_out;

    // workspace (~85 MB)
    f16*   valh  = (f16*)d_ws;                               // MQ*256 fp16
    float* rawo  = (float*)(valh + (size_t)MQ * 256);        // MQ*192 f32 (0.5*tanh)
    f16*   attnh = (f16*)(rawo + (size_t)MQ * 192);          // MQ*96 fp16
    f16*   Af    = attnh + (size_t)MQ * 96;                  // MQ*256 fp16
    f16*   outh  = Af;                                       // reuse after gemm<0>
    f16*   Qh    = Af + (size_t)MQ * 256;                    // MQ*256 fp16
    f16*   Wvt   = Qh + (size_t)MQ * 256;                    // 256*256
    f16*   Wot   = Wvt + 65536;
    f16*   Wch   = Wot + 65536;                              // 288*256
    float* bcat  = (float*)(Wch + 73728);

    dim3 blk(256);

    prep_all<<<dim3(132, 8, 6), blk, 0, stream>>>(feat0, feat1, feat2, query,
                                                  W_val, W_out, W_off, W_attn,
                                                  b_off, b_attn,
                                                  Af, Qh, Wvt, Wot, Wch, bcat);
    gemm_glds<0><<<dim3(5, 263), blk, 0, stream>>>(Af, Qh, Wvt, Wch, b_val, bcat,
                                                   valh, rawo, attnh, nullptr);
    sample_v8<<<dim3(MQ / 8), blk, 0, stream>>>(valh, rawo, attnh, refp, outh);
    gemm_glds<1><<<dim3(2, 263), blk, 0, stream>>>(outh, nullptr, Wot, nullptr,
                                                   b_out, nullptr,
                                                   nullptr, nullptr, nullptr, out);
}